// Round 8
// baseline (310.238 us; speedup 1.0000x reference)
//
#include <hip/hip_runtime.h>

// ONE persistent kernel: peak detect + ordered compaction, (8,16,512,512) fp32.
// History: R2 decoupled lookback 2.9ms (cross-XCD polling — dead end).
// R4/R6/R7 (3- and 2-kernel variants) all exactly 220us => structure-
// insensitive; either harness floor dominates or the mask HBM round-trip +
// second ramp is the shared cost. R8 discriminates: masks live in LDS only,
// one dispatch, manual 512-block grid barrier (2 blocks/CU guaranteed by
// __launch_bounds__(256,2); counts slots 128B-aligned vs XCD false sharing).

namespace {
constexpr int kB = 8;
constexpr int kC = 16;
constexpr int kH = 512;
constexpr int kW = 512;
constexpr int kNPB = kC * kH * kW;                    // 4,194,304 px / batch
constexpr int kMaxPeaks = 262144;
constexpr int kRows = 8;                              // rows per strip
constexpr int kStripsPerBatch = kC * (kH / kRows);    // 1024
constexpr int kNStrips = kB * kStripsPerBatch;        // 8192
constexpr int kSPB = 16;                              // strips per block
constexpr int kNBlocks = kNStrips / kSPB;             // 512 = 2 per CU
constexpr int kBlocksPerBatch = kStripsPerBatch / kSPB;  // 64
constexpr int kTPB = 256;
constexpr int kCntStride = 32;  // ints per block slot (128 B; pads never read)
constexpr long long kPeaksElems = (long long)kB * kMaxPeaks * 3;
constexpr float kNeg = -3.402823466e38f;
}

__device__ __forceinline__ float fmax3(float a, float b, float c) {
  return fmaxf(fmaxf(a, b), c);  // -> v_max3_f32
}

__global__ void __launch_bounds__(kTPB, 2)
peak_fused(const float* __restrict__ hm, unsigned* __restrict__ bar,
           int* __restrict__ cntg, float* __restrict__ out) {
  __shared__ unsigned long long s_w[kSPB][64];  // per-strip ballot masks (8 KB)
  __shared__ int s_cnt[kSPB];
  __shared__ int s_red[kTPB / 64], s_red2[kTPB / 64];

  const int t = threadIdx.x, lane = t & 63, wv = t >> 6;
  const int blk = blockIdx.x;
  const int b = blk / kBlocksPerBatch;          // 64 blocks / batch
  const int jb = blk & (kBlocksPerBatch - 1);

  // ================= phase 1: detect, masks -> LDS, counts -> global ======
  for (int k = 0; k < kSPB / 4; ++k) {
    const int m = wv * 4 + k;
    const int si = (blk * kSPB + m) & (kStripsPerBatch - 1);
    const int c = si >> 6;
    const int y0 = (si & 63) * kRows;
    const float* rp =
        hm + (long long)b * kNPB + c * (kH * kW) + y0 * kW + lane * 8;

    float a[10][8];
#pragma unroll
    for (int i = 1; i <= 8; ++i) {
      const float4 q0 = *reinterpret_cast<const float4*>(rp + (i - 1) * kW);
      const float4 q1 = *reinterpret_cast<const float4*>(rp + (i - 1) * kW + 4);
      a[i][0] = q0.x; a[i][1] = q0.y; a[i][2] = q0.z; a[i][3] = q0.w;
      a[i][4] = q1.x; a[i][5] = q1.y; a[i][6] = q1.z; a[i][7] = q1.w;
    }
    if (y0 > 0) {
      const float4 q0 = *reinterpret_cast<const float4*>(rp - kW);
      const float4 q1 = *reinterpret_cast<const float4*>(rp - kW + 4);
      a[0][0] = q0.x; a[0][1] = q0.y; a[0][2] = q0.z; a[0][3] = q0.w;
      a[0][4] = q1.x; a[0][5] = q1.y; a[0][6] = q1.z; a[0][7] = q1.w;
    } else {
#pragma unroll
      for (int jj = 0; jj < 8; ++jj) a[0][jj] = kNeg;
    }
    if (y0 + kRows < kH) {
      const float4 q0 = *reinterpret_cast<const float4*>(rp + 8 * kW);
      const float4 q1 = *reinterpret_cast<const float4*>(rp + 8 * kW + 4);
      a[9][0] = q0.x; a[9][1] = q0.y; a[9][2] = q0.z; a[9][3] = q0.w;
      a[9][4] = q1.x; a[9][5] = q1.y; a[9][6] = q1.z; a[9][7] = q1.w;
    } else {
#pragma unroll
      for (int jj = 0; jj < 8; ++jj) a[9][jj] = kNeg;
    }

    unsigned long long myword = 0;  // lane (r*8+j) keeps ballot word (r,j)
    int scnt = 0;
#pragma unroll
    for (int r = 0; r < kRows; ++r) {
      float cm[8];
#pragma unroll
      for (int jj = 0; jj < 8; ++jj)
        cm[jj] = fmax3(a[r][jj], a[r + 1][jj], a[r + 2][jj]);
      float hl = __shfl_up(cm[7], 1, 64);
      float hr = __shfl_down(cm[0], 1, 64);
      if (lane == 0) hl = kNeg;
      if (lane == 63) hr = kNeg;
      float mx[8];
      mx[0] = fmax3(hl, cm[0], cm[1]);
#pragma unroll
      for (int jj = 1; jj < 7; ++jj) mx[jj] = fmax3(cm[jj - 1], cm[jj], cm[jj + 1]);
      mx[7] = fmax3(cm[6], cm[7], hr);
#pragma unroll
      for (int jj = 0; jj < 8; ++jj) {
        const float v = a[r + 1][jj];
        const unsigned long long wj = __ballot((v == mx[jj]) && (v > 0.0f));
        scnt += (int)__popcll(wj);
        if (lane == r * 8 + jj) myword = wj;  // wave-uniform, 1-lane capture
      }
    }
    s_w[m][lane] = myword;
    if (lane == 0) s_cnt[m] = scnt;
  }
  __syncthreads();
  if (t < kSPB) cntg[blk * kCntStride + t] = s_cnt[t];

  // ================= grid barrier (single-use; bar pre-zeroed) ============
  __syncthreads();  // cntg stores by t<16 happen-before thread 0's fence
  if (t == 0) {
    __threadfence();  // device-scope release of this block's cntg writes
    const unsigned arrived =
        __hip_atomic_fetch_add(bar, 1u, __ATOMIC_ACQ_REL,
                               __HIP_MEMORY_SCOPE_AGENT) + 1;
    if (arrived < (unsigned)kNBlocks) {
      while (__hip_atomic_load(bar, __ATOMIC_ACQUIRE,
                               __HIP_MEMORY_SCOPE_AGENT) < (unsigned)kNBlocks)
        __builtin_amdgcn_s_sleep(8);
    }
    __threadfence();  // device-scope acquire: invalidate for fresh cntg reads
  }
  __syncthreads();

  // ================= phase 2: offsets + ordered writes ====================
  // Block base = sum of counts of blocks j<jb in this batch. Thread t reads
  // int4 of block j=t>>2, strips (t&3)*4.. — covers all 64x16 valid counts;
  // 128B slot pads are never touched.
  {
    const int j = t >> 2, i4 = (t & 3) * 4;
    const int4 c4 = *reinterpret_cast<const int4*>(
        cntg + (b * kBlocksPerBatch + j) * kCntStride + i4);
    int tot = c4.x + c4.y + c4.z + c4.w;
    int pre = (j < jb) ? tot : 0;
#pragma unroll
    for (int d = 32; d >= 1; d >>= 1) {
      pre += __shfl_down(pre, d, 64);
      tot += __shfl_down(tot, d, 64);
    }
    if (lane == 0) { s_red[wv] = pre; s_red2[wv] = tot; }
  }
  __syncthreads();
  const int base = s_red[0] + s_red[1] + s_red[2] + s_red[3];
  if (jb == 0 && t == 0)
    out[kPeaksElems + b] =
        (float)(s_red2[0] + s_red2[1] + s_red2[2] + s_red2[3]);  // counts[b]

  int off0 = base;
  for (int i = 0; i < wv * 4; ++i) off0 += s_cnt[i];

  const unsigned long long pm = (lane == 0) ? 0ull : (~0ull >> (64 - lane));
  float* pb = out + (long long)b * kMaxPeaks * 3;
  for (int k = 0; k < kSPB / 4; ++k) {
    const int m = wv * 4 + k;
    if (off0 < kMaxPeaks) {
      const int si = (blk * kSPB + m) & (kStripsPerBatch - 1);
      const int c = si >> 6;
      const int y0 = (si & 63) * kRows;
      const float* rp =
          hm + (long long)b * kNPB + c * (kH * kW) + y0 * kW + lane * 8;

      float4 cv[kRows][2];
#pragma unroll
      for (int r = 0; r < kRows; ++r) {
        cv[r][0] = *reinterpret_cast<const float4*>(rp + r * kW);
        cv[r][1] = *reinterpret_cast<const float4*>(rp + r * kW + 4);
      }

      int rbase = off0;
#pragma unroll
      for (int r = 0; r < kRows; ++r) {
        unsigned long long w[8];
#pragma unroll
        for (int jj = 0; jj < 8; ++jj) w[jj] = s_w[m][r * 8 + jj];
        int lexcl = 0, rowcnt = 0;
#pragma unroll
        for (int jj = 0; jj < 8; ++jj) {
          lexcl += (int)__popcll(w[jj] & pm);
          rowcnt += (int)__popcll(w[jj]);
        }
        int rank = rbase + lexcl;
        const float vv[8] = {cv[r][0].x, cv[r][0].y, cv[r][0].z, cv[r][0].w,
                             cv[r][1].x, cv[r][1].y, cv[r][1].z, cv[r][1].w};
        const float fy = (float)(y0 + r);
#pragma unroll
        for (int jj = 0; jj < 8; ++jj) {
          const int f = (int)((w[jj] >> lane) & 1);
          if (f && rank < kMaxPeaks) {
            float* o = pb + (long long)rank * 3;
            o[0] = (float)(lane * 8 + jj);
            o[1] = fy;
            o[2] = vv[jj];
          }
          rank += f;
        }
        rbase += rowcnt;
        if (rbase >= kMaxPeaks) break;  // uniform: later rows past the cap
      }
    }
    off0 += s_cnt[m];
  }
}

extern "C" void kernel_launch(void* const* d_in, const int* in_sizes, int n_in,
                              void* d_out, int out_size, void* d_ws, size_t ws_size,
                              hipStream_t stream) {
  const float* hm = (const float*)d_in[0];
  float* out = (float*)d_out;

  // ws: [0,128) barrier counter (zeroed each call); [128, 128+64KB) counts,
  // 128B-aligned 32-int slot per block (only 16 valid ints ever read).
  unsigned* bar = (unsigned*)d_ws;
  int* cntg = (int*)((char*)d_ws + 128);

  hipMemsetAsync(d_ws, 0, 128, stream);  // barrier must start at 0 (ws poisoned)
  peak_fused<<<kNBlocks, kTPB, 0, stream>>>(hm, bar, cntg, out);
}

// Round 9
// 219.833 us; speedup vs baseline: 1.4112x; 1.4112x over previous
//
#include <hip/hip_runtime.h>

// Two-kernel peak detection + ordered compaction, (8,16,512,512) fp32.
// History: R2 decoupled lookback 2.9ms (cross-XCD polling). R4/R6/R7 all
// 220us. R8 fused+grid-barrier 310us BUT gave counters: VGPR_Count=64 on a
// design needing ~100 live regs => allocator SERIALIZED the up-front loads;
// kernel ran 180us even LLC-resident (785 GB/s, latency-bound). Harness
// fixed floor ~130us (310-180). R9: rolling 3-row window + distance-2
// prefetch in both streaming kernels — low liveness (~50 VGPR), steady
// 2 loads/row in flight, full occupancy, back to 2 dispatches.

namespace {
constexpr int kB = 8;
constexpr int kC = 16;
constexpr int kH = 512;
constexpr int kW = 512;
constexpr int kNPB = kC * kH * kW;              // 4,194,304 px / batch
constexpr int kMaxPeaks = 262144;
constexpr int kRows = 8;                        // rows per strip
constexpr int kStripsPerBatch = kC * (kH / kRows);   // 1024
constexpr int kNStrips = kB * kStripsPerBatch;  // 8192
constexpr int kWPB = 4;                         // waves (strips) per block
constexpr int kTPB = 64 * kWPB;                 // 256
constexpr long long kPeaksElems = (long long)kB * kMaxPeaks * 3;
constexpr float kNeg = -3.402823466e38f;
}

__device__ __forceinline__ float fmax3(float a, float b, float c) {
  return fmaxf(fmaxf(a, b), c);  // -> v_max3_f32
}

// Load 8 px of strip-relative row i (absolute y = y0+i) or -FLT_MAX outside.
__device__ __forceinline__ void loadrow(const float* __restrict__ rp, int y0,
                                        int i, float d[8]) {
  const int yy = y0 + i;
  if (yy >= 0 && yy < kH) {
    const float4 q0 = *reinterpret_cast<const float4*>(rp + i * kW);
    const float4 q1 = *reinterpret_cast<const float4*>(rp + i * kW + 4);
    d[0] = q0.x; d[1] = q0.y; d[2] = q0.z; d[3] = q0.w;
    d[4] = q1.x; d[5] = q1.y; d[6] = q1.z; d[7] = q1.w;
  } else {
#pragma unroll
    for (int j = 0; j < 8; ++j) d[j] = kNeg;
  }
}

// Pass 1: wave = one 8-row strip; lane l owns x=l*8..+7. Rolling window
// rows (r-1,r,r+1) + prefetch rows r+2,r+3. Emits 64 u64 mask words/strip
// (word r*8+j: bit l = flag of px (y0+r, x=l*8+j)) + strip count.
__global__ void __launch_bounds__(kTPB)
peak_count_kernel(const float* __restrict__ hm,
                  unsigned long long* __restrict__ bmw,
                  int* __restrict__ cnts) {
  const int t = threadIdx.x, lane = t & 63, wv = t >> 6;
  const int s = blockIdx.x * kWPB + wv;
  const int b = s >> 10;                 // 1024 strips / batch
  const int si = s & 1023;
  const int c = si >> 6;                 // 64 strips / image
  const int y0 = (si & 63) * kRows;
  const float* rp = hm + (long long)b * kNPB + c * (kH * kW) + y0 * kW + lane * 8;

  float A[8], Bv[8], Cv[8], N1[8], N2[8];
  loadrow(rp, y0, -1, A);
  loadrow(rp, y0, 0, Bv);
  loadrow(rp, y0, 1, Cv);
  loadrow(rp, y0, 2, N1);
  loadrow(rp, y0, 3, N2);

  unsigned long long myword = 0;  // lane (r*8+j) keeps ballot word (r,j)
  int scnt = 0;                   // wave-uniform strip count
#pragma unroll
  for (int r = 0; r < kRows; ++r) {
    float cm[8];
#pragma unroll
    for (int j = 0; j < 8; ++j) cm[j] = fmax3(A[j], Bv[j], Cv[j]);
    float hl = __shfl_up(cm[7], 1, 64);
    float hr = __shfl_down(cm[0], 1, 64);
    if (lane == 0) hl = kNeg;    // x = -1 (image edge)
    if (lane == 63) hr = kNeg;   // x = 512 (image edge)
    float m[8];
    m[0] = fmax3(hl, cm[0], cm[1]);
#pragma unroll
    for (int j = 1; j < 7; ++j) m[j] = fmax3(cm[j - 1], cm[j], cm[j + 1]);
    m[7] = fmax3(cm[6], cm[7], hr);
#pragma unroll
    for (int j = 0; j < 8; ++j) {
      const float v = Bv[j];
      const unsigned long long wj = __ballot((v == m[j]) && (v > 0.0f));
      scnt += (int)__popcll(wj);
      if (lane == r * 8 + j) myword = wj;  // wave-uniform value, 1-lane capture
    }
    // rotate window + prefetch row r+4 (needed rows end at index 8)
#pragma unroll
    for (int j = 0; j < 8; ++j) { A[j] = Bv[j]; Bv[j] = Cv[j]; Cv[j] = N1[j]; N1[j] = N2[j]; }
    if (r <= 4) loadrow(rp, y0, r + 4, N2);  // compile-time predicate (unrolled)
  }
  bmw[(long long)s * 64 + lane] = myword;
  if (lane == 0) cnts[s] = scnt;
}

// Pass 2+3 fused: each block owns 4 consecutive strips of one batch.
// Base offset computed redundantly per block (masked reduce over the batch's
// 1024 counts, L2-warm); then rank-ordered writes, conf rows prefetch-depth-2.
__global__ void __launch_bounds__(kTPB)
peak_write_kernel(const float* __restrict__ hm,
                  const unsigned long long* __restrict__ bmw,
                  const int* __restrict__ cnts,
                  float* __restrict__ out) {
  __shared__ int s_pre[kWPB], s_tot[kWPB], s_c[kWPB];
  __shared__ unsigned long long s_w[kWPB][64];
  const int t = threadIdx.x, lane = t & 63, wv = t >> 6;
  const int g = blockIdx.x;
  const int b = g >> 8;                  // 256 groups / batch
  const int g0 = (g & 255) * kWPB;       // first strip (within batch) of block
  const int* cb = cnts + b * kStripsPerBatch;

  // thread t owns counts[t*4 .. t*4+3]; g0 % 4 == 0 -> mask is thread-uniform
  const int4 c4 = *reinterpret_cast<const int4*>(cb + t * 4);
  const int idx0 = t * 4;
  int tot = c4.x + c4.y + c4.z + c4.w;
  int pre = (idx0 < g0) ? tot : 0;
  if (idx0 == g0) { s_c[0] = c4.x; s_c[1] = c4.y; s_c[2] = c4.z; s_c[3] = c4.w; }
#pragma unroll
  for (int d = 32; d >= 1; d >>= 1) {
    pre += __shfl_down(pre, d, 64);
    tot += __shfl_down(tot, d, 64);
  }
  if (lane == 0) { s_pre[wv] = pre; s_tot[wv] = tot; }
  __syncthreads();
  const int base = s_pre[0] + s_pre[1] + s_pre[2] + s_pre[3];
  if (g0 == 0 && t == 0)
    out[kPeaksElems + b] =
        (float)(s_tot[0] + s_tot[1] + s_tot[2] + s_tot[3]);  // counts[b]

  int off0 = base;
  for (int k = 0; k < wv; ++k) off0 += s_c[k];
  if (off0 >= kMaxPeaks) return;  // wave-uniform; no barriers below

  const int s = b * kStripsPerBatch + g0 + wv;
  const int si = g0 + wv, c = si >> 6, y0 = (si & 63) * kRows;
  const float* rp = hm + (long long)b * kNPB + c * (kH * kW) + y0 * kW + lane * 8;

  // mask words -> per-wave LDS region; same-wave produce/consume (lgkmcnt only)
  s_w[wv][lane] = bmw[(long long)s * 64 + lane];

  // conf rows: rolling prefetch, depth 2
  float P0[8], P1[8], cur[8];
  loadrow(rp, y0, 0, P0);
  loadrow(rp, y0, 1, P1);

  const unsigned long long pm = (lane == 0) ? 0ull : (~0ull >> (64 - lane));
  int rbase = off0;
  float* pb = out + (long long)b * kMaxPeaks * 3;
#pragma unroll
  for (int r = 0; r < kRows; ++r) {
#pragma unroll
    for (int j = 0; j < 8; ++j) { cur[j] = P0[j]; P0[j] = P1[j]; }
    if (r < kRows - 2) loadrow(rp, y0, r + 2, P1);  // compile-time predicate

    unsigned long long w[8];
#pragma unroll
    for (int j = 0; j < 8; ++j) w[j] = s_w[wv][r * 8 + j];
    int lexcl = 0, rowcnt = 0;
#pragma unroll
    for (int j = 0; j < 8; ++j) {
      lexcl += (int)__popcll(w[j] & pm);
      rowcnt += (int)__popcll(w[j]);
    }
    int rank = rbase + lexcl;
    const float fy = (float)(y0 + r);
#pragma unroll
    for (int j = 0; j < 8; ++j) {
      const int f = (int)((w[j] >> lane) & 1);
      if (f && rank < kMaxPeaks) {
        float* o = pb + (long long)rank * 3;
        o[0] = (float)(lane * 8 + j);
        o[1] = fy;
        o[2] = cur[j];
      }
      rank += f;
    }
    rbase += rowcnt;
    if (rbase >= kMaxPeaks) break;  // uniform: all later rows past the cap
  }
}

extern "C" void kernel_launch(void* const* d_in, const int* in_sizes, int n_in,
                              void* d_out, int out_size, void* d_ws, size_t ws_size,
                              hipStream_t stream) {
  const float* hm = (const float*)d_in[0];
  float* out = (float*)d_out;

  // ws: masks 8192*64 u64 (4 MB) | strip counts 8192 int
  unsigned long long* bmw = (unsigned long long*)d_ws;
  int* cnts = (int*)(bmw + (long long)kNStrips * 64);

  peak_count_kernel<<<kNStrips / kWPB, kTPB, 0, stream>>>(hm, bmw, cnts);
  peak_write_kernel<<<kNStrips / kWPB, kTPB, 0, stream>>>(hm, bmw, cnts, out);
}